// Round 2
// baseline (103.018 us; speedup 1.0000x reference)
//
#include <hip/hip_runtime.h>

#define NB   4
#define KCH  4
#define HS   64
#define WSZ  64
#define P    4096          // HS*WSZ
#define REC  12            // floats per record: x,y,r,g,b,sq,s0..s3,pad,pad
#define QT   256           // q per block
#define BLK  256           // threads per block
#define PT   2             // p per thread

// Build per-point records: feats (scaled) + |f|^2 + 2x2-mean segmentation.
__global__ __launch_bounds__(256) void crf_prep(const float* __restrict__ images,
                                                const float* __restrict__ segs,
                                                float* __restrict__ rec) {
    int idx = blockIdx.x * blockDim.x + threadIdx.x;   // n*P + p
    if (idx >= NB * P) return;
    int n = idx >> 12;
    int p = idx & (P - 1);
    int i = p >> 6;      // row in downsampled image
    int j = p & 63;      // col
    const float* img = images + (size_t)n * 3 * 128 * 128;
    int off = (2 * i) * 128 + 2 * j;
    float x = (float)j * (1.0f / 50.0f);               // SIGMA_XY*SCALE = 50
    float y = (float)i * (1.0f / 50.0f);
    float r = img[0 * 16384 + off] * (1.0f / 15.0f);   // SIGMA_RGB = 15
    float g = img[1 * 16384 + off] * (1.0f / 15.0f);
    float b = img[2 * 16384 + off] * (1.0f / 15.0f);
    float sq = x * x + y * y + r * r + g * g + b * b;
    float* o = rec + (size_t)idx * REC;
    o[0] = x; o[1] = y; o[2] = r; o[3] = g; o[4] = b; o[5] = sq;
    const float* sg = segs + (size_t)n * KCH * 128 * 128;
#pragma unroll
    for (int k = 0; k < KCH; ++k) {
        const float* s = sg + k * 16384 + off;
        o[6 + k] = 0.25f * (s[0] + s[1] + s[128] + s[129]);
    }
    o[10] = 0.0f; o[11] = 0.0f;
}

// Fused pairwise-Gaussian x seg-dot reduction. grid = (32 p-blocks, 16 q-chunks).
__global__ __launch_bounds__(256) void crf_main(const float* __restrict__ rec,
                                                float* __restrict__ out) {
    __shared__ float lds[QT * REC];      // 12 KB
    __shared__ float wsum[BLK / 64];

    int t = threadIdx.x;
    int pb = blockIdx.x;                 // 0..31  (8 p-blocks of 512 per batch)
    int n = pb >> 3;
    int pbase = (pb & 7) * (BLK * PT);
    int qbase = blockIdx.y * QT;
    const float* base = rec + (size_t)n * P * REC;

    // Stage q-records into LDS (coalesced float4 copy: 768 float4s / 256 thr).
    const float4* src4 = (const float4*)(base + (size_t)qbase * REC);
    float4* lds4 = (float4*)lds;
#pragma unroll
    for (int it = 0; it < (QT * REC / 4) / BLK; ++it)
        lds4[t + it * BLK] = src4[t + it * BLK];

    // Own p-records into registers.
    float rp0[10], rp1[10];
    {
        const float* r0 = base + (size_t)(pbase + t) * REC;
        const float* r1 = base + (size_t)(pbase + t + BLK) * REC;
#pragma unroll
        for (int i = 0; i < 10; ++i) { rp0[i] = r0[i]; rp1[i] = r1[i]; }
    }
    __syncthreads();

    float acc0 = 0.0f, acc1 = 0.0f;
#pragma unroll 4
    for (int q = 0; q < QT; ++q) {
        const float4* rq = (const float4*)(lds + q * REC);   // 48B-aligned
        float4 f0 = rq[0];       // x y r g
        float4 f1 = rq[1];       // b sq s0 s1
        float4 f2 = rq[2];       // s2 s3 pad pad
        {
            float dot = rp0[0]*f0.x + rp0[1]*f0.y + rp0[2]*f0.z + rp0[3]*f0.w + rp0[4]*f1.x;
            float d2 = fmaxf(rp0[5] + f1.y - 2.0f * dot, 0.0f);
            float w = __expf(-0.5f * d2);
            float sd = rp0[6]*f1.z + rp0[7]*f1.w + rp0[8]*f2.x + rp0[9]*f2.y;
            acc0 = fmaf(w, sd, acc0);
        }
        {
            float dot = rp1[0]*f0.x + rp1[1]*f0.y + rp1[2]*f0.z + rp1[3]*f0.w + rp1[4]*f1.x;
            float d2 = fmaxf(rp1[5] + f1.y - 2.0f * dot, 0.0f);
            float w = __expf(-0.5f * d2);
            float sd = rp1[6]*f1.z + rp1[7]*f1.w + rp1[8]*f2.x + rp1[9]*f2.y;
            acc1 = fmaf(w, sd, acc1);
        }
    }

    float acc = acc0 + acc1;
#pragma unroll
    for (int off = 32; off > 0; off >>= 1)
        acc += __shfl_down(acc, off, 64);
    if ((t & 63) == 0) wsum[t >> 6] = acc;
    __syncthreads();
    if (t == 0) {
        float s = wsum[0] + wsum[1] + wsum[2] + wsum[3];
        // loss = WEIGHT * (-sum / n) = -1e-7/4 * sum
        atomicAdd(out, s * (-2.5e-8f));
    }
}

extern "C" void kernel_launch(void* const* d_in, const int* in_sizes, int n_in,
                              void* d_out, int out_size, void* d_ws, size_t ws_size,
                              hipStream_t stream) {
    const float* images = (const float*)d_in[0];
    const float* segs   = (const float*)d_in[1];
    float* out = (float*)d_out;
    float* rec = (float*)d_ws;          // 16384 * 12 * 4 B = 768 KB

    (void)hipMemsetAsync(out, 0, sizeof(float), stream);
    crf_prep<<<dim3((NB * P + 255) / 256), dim3(256), 0, stream>>>(images, segs, rec);
    crf_main<<<dim3(32, 16), dim3(256), 0, stream>>>(rec, out);
}

// Round 3
// 79.983 us; speedup vs baseline: 1.2880x; 1.2880x over previous
//
#include <hip/hip_runtime.h>

#define NB   4
#define KCH  4
#define P    4096          // 64*64 downsampled points per batch
#define REC  12            // floats per record: fx,fy,fr,fg,fb,h,s0..s3,pad,pad
#define QT   64            // q per block
#define BLK  256           // threads per block
#define PT   4             // p per thread

// Native exp2 if available: pre-scale features by sqrt(log2(e)) so the
// MFMA... er, VALU chain feeds v_exp_f32 directly with no extra mul.
#if __has_builtin(__builtin_amdgcn_exp2f)
#define EXPFN(x) __builtin_amdgcn_exp2f(x)
#define FSCALE 1.2011224087864498f   /* sqrt(log2(e)) */
#else
#define EXPFN(x) __expf(x)
#define FSCALE 1.0f
#endif

// Build per-point records: scaled feats + h = -0.5*|f|^2 + 2x2-mean seg.
// Also zeroes d_out (stream-ordered before crf_main's atomics).
__global__ __launch_bounds__(64) void crf_prep(const float* __restrict__ images,
                                               const float* __restrict__ segs,
                                               float* __restrict__ rec,
                                               float* __restrict__ out) {
    int idx = blockIdx.x * 64 + threadIdx.x;   // n*P + p, 16384 total
    if (idx == 0) out[0] = 0.0f;
    int n = idx >> 12;
    int p = idx & (P - 1);
    int i = p >> 6;      // row in downsampled image
    int j = p & 63;      // col
    const float* img = images + (size_t)n * 3 * 16384;
    int rowoff = 256 * i;                      // byte row start (in floats)
    // Coalesced float2 loads: lane j reads 8B at stride 8B.
    float2 ir = ((const float2*)(img + 0 * 16384 + rowoff))[j];
    float2 ig = ((const float2*)(img + 1 * 16384 + rowoff))[j];
    float2 ib = ((const float2*)(img + 2 * 16384 + rowoff))[j];
    float x = (float)j * (FSCALE / 50.0f);     // SIGMA_XY*SCALE = 50
    float y = (float)i * (FSCALE / 50.0f);
    float r = ir.x * (FSCALE / 15.0f);         // SIGMA_RGB = 15
    float g = ig.x * (FSCALE / 15.0f);
    float b = ib.x * (FSCALE / 15.0f);
    float h = -0.5f * (x * x + y * y + r * r + g * g + b * b);
    float* o = rec + (size_t)idx * REC;
    o[0] = x; o[1] = y; o[2] = r; o[3] = g; o[4] = b; o[5] = h;
    const float* sg = segs + (size_t)n * KCH * 16384;
#pragma unroll
    for (int k = 0; k < KCH; ++k) {
        float2 s0 = ((const float2*)(sg + k * 16384 + rowoff))[j];
        float2 s1 = ((const float2*)(sg + k * 16384 + rowoff + 128))[j];
        o[6 + k] = 0.25f * ((s0.x + s0.y) + (s1.x + s1.y));
    }
    o[10] = 0.0f; o[11] = 0.0f;
}

// Fused pairwise-Gaussian x seg-dot reduction.
// grid = (16 p-tiles [4 per batch, 1024 p each], 64 q-chunks of 64).
__global__ __launch_bounds__(256) void crf_main(const float* __restrict__ rec,
                                                float* __restrict__ out) {
    __shared__ float lds[QT * REC];      // 3 KB
    __shared__ float wsum[BLK / 64];

    int t = threadIdx.x;
    int pb = blockIdx.x;                 // 0..15
    int n = pb >> 2;
    int pbase = (pb & 3) * (BLK * PT);
    int qbase = blockIdx.y * QT;
    const float* base = rec + (size_t)n * P * REC;

    // Stage q-records into LDS (192 float4s).
    const float4* src4 = (const float4*)(base + (size_t)qbase * REC);
    float4* lds4 = (float4*)lds;
    if (t < QT * REC / 4) lds4[t] = src4[t];

    // Own p-records into registers (vectorized: 48B record = f4+f4+f2).
    float rp[PT][10];
#pragma unroll
    for (int pi = 0; pi < PT; ++pi) {
        const float* r0 = base + (size_t)(pbase + t + pi * BLK) * REC;
        float4 a = ((const float4*)r0)[0];
        float4 b = ((const float4*)r0)[1];
        float2 c = ((const float2*)r0)[4];
        rp[pi][0] = a.x; rp[pi][1] = a.y; rp[pi][2] = a.z; rp[pi][3] = a.w;
        rp[pi][4] = b.x; rp[pi][5] = b.y; rp[pi][6] = b.z; rp[pi][7] = b.w;
        rp[pi][8] = c.x; rp[pi][9] = c.y;
    }
    __syncthreads();

    float acc[PT] = {0.f, 0.f, 0.f, 0.f};
#pragma unroll 2
    for (int q = 0; q < QT; ++q) {
        const float4* rq = (const float4*)(lds + q * REC);   // broadcast reads
        float4 f0 = rq[0];       // x y r g
        float4 f1 = rq[1];       // b h s0 s1
        float4 f2 = rq[2];       // s2 s3 pad pad
#pragma unroll
        for (int pi = 0; pi < PT; ++pi) {
            float d = rp[pi][5] + f1.y;                 // h_p + h_q
            d = fmaf(rp[pi][0], f0.x, d);
            d = fmaf(rp[pi][1], f0.y, d);
            d = fmaf(rp[pi][2], f0.z, d);
            d = fmaf(rp[pi][3], f0.w, d);
            d = fmaf(rp[pi][4], f1.x, d);               // log2e*(-0.5*d2)
            float w = EXPFN(d);
            float sd = rp[pi][6] * f1.z;
            sd = fmaf(rp[pi][7], f1.w, sd);
            sd = fmaf(rp[pi][8], f2.x, sd);
            sd = fmaf(rp[pi][9], f2.y, sd);
            acc[pi] = fmaf(w, sd, acc[pi]);
        }
    }

    float acc_all = (acc[0] + acc[1]) + (acc[2] + acc[3]);
#pragma unroll
    for (int off = 32; off > 0; off >>= 1)
        acc_all += __shfl_down(acc_all, off, 64);
    if ((t & 63) == 0) wsum[t >> 6] = acc_all;
    __syncthreads();
    if (t == 0) {
        float s = (wsum[0] + wsum[1]) + (wsum[2] + wsum[3]);
        // loss = WEIGHT * (-sum / n) = -1e-7/4 * sum
        atomicAdd(out, s * (-2.5e-8f));
    }
}

extern "C" void kernel_launch(void* const* d_in, const int* in_sizes, int n_in,
                              void* d_out, int out_size, void* d_ws, size_t ws_size,
                              hipStream_t stream) {
    const float* images = (const float*)d_in[0];
    const float* segs   = (const float*)d_in[1];
    float* out = (float*)d_out;
    float* rec = (float*)d_ws;          // 16384 * 12 * 4 B = 768 KB

    crf_prep<<<dim3(256), dim3(64), 0, stream>>>(images, segs, rec, out);
    crf_main<<<dim3(16, 64), dim3(256), 0, stream>>>(rec, out);
}

// Round 4
// 78.068 us; speedup vs baseline: 1.3196x; 1.0245x over previous
//
#include <hip/hip_runtime.h>

#define NB   4
#define KCH  4
#define P    4096          // 64*64 downsampled points per batch
#define REC  12            // floats per record: fx,fy,fr,fg,fb,h,s0..s3,pad,pad
#define QT   64            // q per block
#define BLK  256           // threads per block
#define PT   2             // p per thread (p-tile = 512)
#define NPT  8             // p-tiles per batch
#define NBLK 288           // triangle blocks per batch: sum(64-8*pt)

#if __has_builtin(__builtin_amdgcn_exp2f)
#define EXPFN(x) __builtin_amdgcn_exp2f(x)
#define FSCALE 1.2011224087864498f   /* sqrt(log2(e)) */
#else
#define EXPFN(x) __expf(x)
#define FSCALE 1.0f
#endif

// Build per-point records: scaled feats + h = -0.5*log2e*|f|^2 + 2x2-mean seg.
// Also zeroes d_out (stream-ordered before crf_main's atomics).
__global__ __launch_bounds__(64) void crf_prep(const float* __restrict__ images,
                                               const float* __restrict__ segs,
                                               float* __restrict__ rec,
                                               float* __restrict__ out) {
    int idx = blockIdx.x * 64 + threadIdx.x;   // n*P + p, 16384 total
    if (idx == 0) out[0] = 0.0f;
    int n = idx >> 12;
    int p = idx & (P - 1);
    int i = p >> 6;      // row in downsampled image
    int j = p & 63;      // col
    const float* img = images + (size_t)n * 3 * 16384;
    int rowoff = 256 * i;
    float2 ir = ((const float2*)(img + 0 * 16384 + rowoff))[j];
    float2 ig = ((const float2*)(img + 1 * 16384 + rowoff))[j];
    float2 ib = ((const float2*)(img + 2 * 16384 + rowoff))[j];
    float x = (float)j * (FSCALE / 50.0f);     // SIGMA_XY*SCALE = 50
    float y = (float)i * (FSCALE / 50.0f);
    float r = ir.x * (FSCALE / 15.0f);         // SIGMA_RGB = 15
    float g = ig.x * (FSCALE / 15.0f);
    float b = ib.x * (FSCALE / 15.0f);
    float h = -0.5f * (x * x + y * y + r * r + g * g + b * b);
    float* o = rec + (size_t)idx * REC;
    o[0] = x; o[1] = y; o[2] = r; o[3] = g; o[4] = b; o[5] = h;
    const float* sg = segs + (size_t)n * KCH * 16384;
#pragma unroll
    for (int k = 0; k < KCH; ++k) {
        float2 s0 = ((const float2*)(sg + k * 16384 + rowoff))[j];
        float2 s1 = ((const float2*)(sg + k * 16384 + rowoff + 128))[j];
        o[6 + k] = 0.25f * ((s0.x + s0.y) + (s1.x + s1.y));
    }
    o[10] = 0.0f; o[11] = 0.0f;
}

// Symmetric fused pairwise-Gaussian x seg-dot reduction over the block
// triangle. grid = (288 triangle pairs, 4 batches).
__global__ __launch_bounds__(256) void crf_main(const float* __restrict__ rec,
                                                float* __restrict__ out) {
    __shared__ float lds[QT * REC];      // 3 KB
    __shared__ float wsum[BLK / 64];

    int t = threadIdx.x;
    int n = blockIdx.y;

    // Decode triangle block index -> (p-tile pt, q-chunk qc), qc >= 8*pt.
    static const int cum[NPT] = {0, 64, 120, 168, 208, 240, 264, 280};
    int b = blockIdx.x;                  // 0..287
    int pt = 0;
#pragma unroll
    for (int i = 1; i < NPT; ++i) pt += (b >= cum[i]) ? 1 : 0;
    int qc = b - cum[pt] + 8 * pt;
    int pbase = pt * (BLK * PT);
    int qbase = qc * QT;
    bool mixed = (qc >> 3) == pt;        // q-chunk overlaps the p-tile

    const float* base = rec + (size_t)n * P * REC;

    // Stage q-records into LDS (192 float4s).
    const float4* src4 = (const float4*)(base + (size_t)qbase * REC);
    float4* lds4 = (float4*)lds;
    if (t < QT * REC / 4) lds4[t] = src4[t];

    // Own p-records into registers.
    float rp[PT][10];
#pragma unroll
    for (int pi = 0; pi < PT; ++pi) {
        const float* r0 = base + (size_t)(pbase + t + pi * BLK) * REC;
        float4 a = ((const float4*)r0)[0];
        float4 b4 = ((const float4*)r0)[1];
        float2 c = ((const float2*)r0)[4];
        rp[pi][0] = a.x; rp[pi][1] = a.y; rp[pi][2] = a.z; rp[pi][3] = a.w;
        rp[pi][4] = b4.x; rp[pi][5] = b4.y; rp[pi][6] = b4.z; rp[pi][7] = b4.w;
        rp[pi][8] = c.x; rp[pi][9] = c.y;
    }
    __syncthreads();

    float acc[PT] = {0.f, 0.f};
    float acc_all;

    if (!mixed) {
        // Strictly above the diagonal: every pair counts twice.
#pragma unroll 4
        for (int q = 0; q < QT; ++q) {
            const float4* rq = (const float4*)(lds + q * REC);
            float4 f0 = rq[0];
            float4 f1 = rq[1];
            float4 f2 = rq[2];
#pragma unroll
            for (int pi = 0; pi < PT; ++pi) {
                float d = rp[pi][5] + f1.y;
                d = fmaf(rp[pi][0], f0.x, d);
                d = fmaf(rp[pi][1], f0.y, d);
                d = fmaf(rp[pi][2], f0.z, d);
                d = fmaf(rp[pi][3], f0.w, d);
                d = fmaf(rp[pi][4], f1.x, d);
                float w = EXPFN(d);
                float sd = rp[pi][6] * f1.z;
                sd = fmaf(rp[pi][7], f1.w, sd);
                sd = fmaf(rp[pi][8], f2.x, sd);
                sd = fmaf(rp[pi][9], f2.y, sd);
                acc[pi] = fmaf(w, sd, acc[pi]);
            }
        }
        acc_all = 2.0f * (acc[0] + acc[1]);
    } else {
        // Diagonal-overlap block: weight pairs 2/1/0 for q>p / q==p / q<p.
#pragma unroll 4
        for (int q = 0; q < QT; ++q) {
            const float4* rq = (const float4*)(lds + q * REC);
            float4 f0 = rq[0];
            float4 f1 = rq[1];
            float4 f2 = rq[2];
            int qg = qbase + q;
#pragma unroll
            for (int pi = 0; pi < PT; ++pi) {
                int pg = pbase + t + pi * BLK;
                float d = rp[pi][5] + f1.y;
                d = fmaf(rp[pi][0], f0.x, d);
                d = fmaf(rp[pi][1], f0.y, d);
                d = fmaf(rp[pi][2], f0.z, d);
                d = fmaf(rp[pi][3], f0.w, d);
                d = fmaf(rp[pi][4], f1.x, d);
                float w = EXPFN(d);
                float sd = rp[pi][6] * f1.z;
                sd = fmaf(rp[pi][7], f1.w, sd);
                sd = fmaf(rp[pi][8], f2.x, sd);
                sd = fmaf(rp[pi][9], f2.y, sd);
                float f = (qg > pg) ? 2.0f : ((qg == pg) ? 1.0f : 0.0f);
                acc[pi] = fmaf(w, sd * f, acc[pi]);
            }
        }
        acc_all = acc[0] + acc[1];
    }

#pragma unroll
    for (int off = 32; off > 0; off >>= 1)
        acc_all += __shfl_down(acc_all, off, 64);
    if ((t & 63) == 0) wsum[t >> 6] = acc_all;
    __syncthreads();
    if (t == 0) {
        float s = (wsum[0] + wsum[1]) + (wsum[2] + wsum[3]);
        // loss = WEIGHT * (-sum / n) = -1e-7/4 * sum
        atomicAdd(out, s * (-2.5e-8f));
    }
}

extern "C" void kernel_launch(void* const* d_in, const int* in_sizes, int n_in,
                              void* d_out, int out_size, void* d_ws, size_t ws_size,
                              hipStream_t stream) {
    const float* images = (const float*)d_in[0];
    const float* segs   = (const float*)d_in[1];
    float* out = (float*)d_out;
    float* rec = (float*)d_ws;          // 16384 * 12 * 4 B = 768 KB

    crf_prep<<<dim3(256), dim3(64), 0, stream>>>(images, segs, rec, out);
    crf_main<<<dim3(NBLK, NB), dim3(256), 0, stream>>>(rec, out);
}

// Round 5
// 76.595 us; speedup vs baseline: 1.3450x; 1.0192x over previous
//
#include <hip/hip_runtime.h>

#define NB   4
#define KCH  4
#define P    4096          // 64*64 downsampled points per batch
#define REC  12            // LDS floats per q-record: fx,fy,fr,fg,fb,h,s0..s3,pad,pad
#define QT   64            // q per block
#define BLK  256           // threads per block
#define PT   2             // p per thread (p-tile = 512)
#define NPT  8             // p-tiles per batch
#define NBLK 288           // triangle blocks per batch: sum(64-8*pt)

#if __has_builtin(__builtin_amdgcn_exp2f)
#define EXPFN(x) __builtin_amdgcn_exp2f(x)
#define FSCALE 1.2011224087864498f   /* sqrt(log2(e)) */
#else
#define EXPFN(x) __expf(x)
#define FSCALE 1.0f
#endif

// Compute one downsampled-point record directly from raw inputs.
// feats pre-scaled by FSCALE so exp2 needs no extra multiply;
// h = -0.5*|f|^2 (in log2 units).
__device__ __forceinline__ void make_rec(const float* __restrict__ images,
                                         const float* __restrict__ segs,
                                         int n, int p, float* o /*[10]*/) {
    int i = p >> 6;
    int j = p & 63;
    int off = 256 * i + 2 * j;           // element offset of pixel (2i, 2j)
    const float* img = images + (size_t)n * 3 * 16384;
    float x = (float)j * (FSCALE / 50.0f);     // SIGMA_XY*SCALE = 50
    float y = (float)i * (FSCALE / 50.0f);
    float r = img[0 * 16384 + off] * (FSCALE / 15.0f);   // SIGMA_RGB = 15
    float g = img[1 * 16384 + off] * (FSCALE / 15.0f);
    float b = img[2 * 16384 + off] * (FSCALE / 15.0f);
    float h = -0.5f * (x * x + y * y + r * r + g * g + b * b);
    o[0] = x; o[1] = y; o[2] = r; o[3] = g; o[4] = b; o[5] = h;
    const float* sg = segs + (size_t)n * KCH * 16384;
#pragma unroll
    for (int k = 0; k < KCH; ++k) {
        float2 s0 = *(const float2*)(sg + k * 16384 + off);
        float2 s1 = *(const float2*)(sg + k * 16384 + off + 128);
        o[6 + k] = 0.25f * ((s0.x + s0.y) + (s1.x + s1.y));
    }
}

// Single fused kernel: inline prep (p-records in regs, q-records in LDS) +
// symmetric pairwise-Gaussian x seg-dot reduction over the block triangle.
// grid = (288 triangle blocks, 4 batches).
__global__ __launch_bounds__(256) void crf_fused(const float* __restrict__ images,
                                                 const float* __restrict__ segs,
                                                 float* __restrict__ out) {
    __shared__ float lds[QT * REC];      // 3 KB
    __shared__ float wsum[BLK / 64];

    int t = threadIdx.x;
    int n = blockIdx.y;

    // Decode triangle block index -> (p-tile pt, q-chunk qc), qc >= 8*pt.
    static const int cum[NPT] = {0, 64, 120, 168, 208, 240, 264, 280};
    int b = blockIdx.x;                  // 0..287
    int pt = 0;
#pragma unroll
    for (int i = 1; i < NPT; ++i) pt += (b >= cum[i]) ? 1 : 0;
    int qc = b - cum[pt] + 8 * pt;
    int pbase = pt * (BLK * PT);
    int qbase = qc * QT;
    bool mixed = (qc >> 3) == pt;        // q-chunk overlaps the p-tile

    // q-records: first QT threads each build one record into LDS.
    if (t < QT) {
        float o[10];
        make_rec(images, segs, n, qbase + t, o);
        float* l = lds + t * REC;
        *(float4*)(l + 0) = make_float4(o[0], o[1], o[2], o[3]);
        *(float4*)(l + 4) = make_float4(o[4], o[5], o[6], o[7]);
        *(float2*)(l + 8) = make_float2(o[8], o[9]);
    }

    // p-records: every thread builds its PT own records into registers.
    float rp[PT][10];
#pragma unroll
    for (int pi = 0; pi < PT; ++pi)
        make_rec(images, segs, n, pbase + t + pi * BLK, rp[pi]);
    __syncthreads();

    float acc[PT] = {0.f, 0.f};
    float acc_all;

    if (!mixed) {
        // Strictly above the diagonal: every pair counts twice.
#pragma unroll 4
        for (int q = 0; q < QT; ++q) {
            const float4* rq = (const float4*)(lds + q * REC);  // broadcast
            float4 f0 = rq[0];
            float4 f1 = rq[1];
            float4 f2 = rq[2];
#pragma unroll
            for (int pi = 0; pi < PT; ++pi) {
                float d = rp[pi][5] + f1.y;
                d = fmaf(rp[pi][0], f0.x, d);
                d = fmaf(rp[pi][1], f0.y, d);
                d = fmaf(rp[pi][2], f0.z, d);
                d = fmaf(rp[pi][3], f0.w, d);
                d = fmaf(rp[pi][4], f1.x, d);
                float w = EXPFN(d);
                float sd = rp[pi][6] * f1.z;
                sd = fmaf(rp[pi][7], f1.w, sd);
                sd = fmaf(rp[pi][8], f2.x, sd);
                sd = fmaf(rp[pi][9], f2.y, sd);
                acc[pi] = fmaf(w, sd, acc[pi]);
            }
        }
        acc_all = 2.0f * (acc[0] + acc[1]);
    } else {
        // Diagonal-overlap block: weight pairs 2/1/0 for q>p / q==p / q<p.
#pragma unroll 4
        for (int q = 0; q < QT; ++q) {
            const float4* rq = (const float4*)(lds + q * REC);
            float4 f0 = rq[0];
            float4 f1 = rq[1];
            float4 f2 = rq[2];
            int qg = qbase + q;
#pragma unroll
            for (int pi = 0; pi < PT; ++pi) {
                int pg = pbase + t + pi * BLK;
                float d = rp[pi][5] + f1.y;
                d = fmaf(rp[pi][0], f0.x, d);
                d = fmaf(rp[pi][1], f0.y, d);
                d = fmaf(rp[pi][2], f0.z, d);
                d = fmaf(rp[pi][3], f0.w, d);
                d = fmaf(rp[pi][4], f1.x, d);
                float w = EXPFN(d);
                float sd = rp[pi][6] * f1.z;
                sd = fmaf(rp[pi][7], f1.w, sd);
                sd = fmaf(rp[pi][8], f2.x, sd);
                sd = fmaf(rp[pi][9], f2.y, sd);
                float f = (qg > pg) ? 2.0f : ((qg == pg) ? 1.0f : 0.0f);
                acc[pi] = fmaf(w, sd * f, acc[pi]);
            }
        }
        acc_all = acc[0] + acc[1];
    }

#pragma unroll
    for (int off = 32; off > 0; off >>= 1)
        acc_all += __shfl_down(acc_all, off, 64);
    if ((t & 63) == 0) wsum[t >> 6] = acc_all;
    __syncthreads();
    if (t == 0) {
        float s = (wsum[0] + wsum[1]) + (wsum[2] + wsum[3]);
        // loss = WEIGHT * (-sum / n) = -1e-7/4 * sum
        atomicAdd(out, s * (-2.5e-8f));
    }
}

extern "C" void kernel_launch(void* const* d_in, const int* in_sizes, int n_in,
                              void* d_out, int out_size, void* d_ws, size_t ws_size,
                              hipStream_t stream) {
    const float* images = (const float*)d_in[0];
    const float* segs   = (const float*)d_in[1];
    float* out = (float*)d_out;
    (void)d_ws; (void)ws_size;

    (void)hipMemsetAsync(out, 0, sizeof(float), stream);
    crf_fused<<<dim3(NBLK, NB), dim3(256), 0, stream>>>(images, segs, out);
}